// Round 3
// baseline (1795.071 us; speedup 1.0000x reference)
//
#include <hip/hip_runtime.h>

#define N_NODES 100000
#define N_EDGES 1600000
#define DIM 64
#define NLAYERS 5
#define NUM_GRAPHS 256
#define BN_EPS 1e-5f
#define CSR_CAP 32
#define OV_CAP 65536
#define NBLK ((N_NODES + 255) / 256)   /* 391 */

// ---------------------------------------------------------------------------
// CSR build, 4 edges per thread: the 4 atomicAdds issue back-to-back so 4
// round-trips are in flight (was 1 -> latency-bound at 125us).
// cursor must be zeroed before; ends as true in-degree. Slots >= CSR_CAP go
// to the overflow (t,s) pair list, consumed inside aggregate_kernel.
// ---------------------------------------------------------------------------
__global__ __launch_bounds__(256) void build_csr_kernel(
        const int* __restrict__ ei, int* __restrict__ cursor,
        int* __restrict__ csr, int* __restrict__ ovcnt, int* __restrict__ ovpairs) {
    const int Q = N_EDGES / 4;  // 400000
    int tid = blockIdx.x * 256 + threadIdx.x;
    if (tid >= Q) return;
    int e0 = tid, e1 = tid + Q, e2 = tid + 2 * Q, e3 = tid + 3 * Q;
    int s0 = ei[e0], s1 = ei[e1], s2 = ei[e2], s3 = ei[e3];
    int t0 = ei[N_EDGES + e0], t1 = ei[N_EDGES + e1];
    int t2 = ei[N_EDGES + e2], t3 = ei[N_EDGES + e3];
    int c0 = atomicAdd(&cursor[t0], 1);
    int c1 = atomicAdd(&cursor[t1], 1);
    int c2 = atomicAdd(&cursor[t2], 1);
    int c3 = atomicAdd(&cursor[t3], 1);
    if (c0 < CSR_CAP) csr[t0 * CSR_CAP + c0] = s0;
    else { int o = atomicAdd(ovcnt, 1); if (o < OV_CAP) { ovpairs[2*o] = t0; ovpairs[2*o+1] = s0; } }
    if (c1 < CSR_CAP) csr[t1 * CSR_CAP + c1] = s1;
    else { int o = atomicAdd(ovcnt, 1); if (o < OV_CAP) { ovpairs[2*o] = t1; ovpairs[2*o+1] = s1; } }
    if (c2 < CSR_CAP) csr[t2 * CSR_CAP + c2] = s2;
    else { int o = atomicAdd(ovcnt, 1); if (o < OV_CAP) { ovpairs[2*o] = t2; ovpairs[2*o+1] = s2; } }
    if (c3 < CSR_CAP) csr[t3 * CSR_CAP + c3] = s3;
    else { int o = atomicAdd(ovcnt, 1); if (o < OV_CAP) { ovpairs[2*o] = t3; ovpairs[2*o+1] = s3; } }
}

// Pad each node's slot list up to a multiple of 8 with node 0 (valid row);
// padded slots are predicated off in aggregate_kernel.
__global__ void pad_csr_kernel(const int* __restrict__ cursor, int* __restrict__ csr) {
    int n = blockIdx.x * 256 + threadIdx.x;
    if (n >= N_NODES) return;
    int cnt = min(cursor[n], CSR_CAP);
    int cnt8 = (cnt + 7) & ~7;
    for (int k = cnt; k < cnt8; ++k) csr[n * CSR_CAP + k] = 0;
}

// ---------------------------------------------------------------------------
// Aggregate: wave = node, lane = dim. 8 independent 256B row gathers in
// flight; wave-uniform predication. Rare deg>CSR_CAP nodes scan the overflow
// pair list (wave-uniform broadcast reads).
// ---------------------------------------------------------------------------
__global__ __launch_bounds__(256) void aggregate_kernel(
        const int* __restrict__ csr, const int* __restrict__ deg,
        const int* __restrict__ ovcnt, const int* __restrict__ ovpairs,
        const float* __restrict__ h, int hstride, float* __restrict__ agg) {
    long tid = (long)blockIdx.x * 256 + threadIdx.x;
    int n = (int)(tid >> 6);
    int d = (int)(tid & 63);
    if (n >= N_NODES) return;
    int dval = deg[n];
    int cnt = min(dval, CSR_CAP);
    int cnt8 = (cnt + 7) & ~7;
    const int4* row = (const int4*)(csr + n * CSR_CAP);  // 128B-aligned
    float a0 = 0.f, a1 = 0.f, a2 = 0.f, a3 = 0.f;
    float a4 = 0.f, a5 = 0.f, a6 = 0.f, a7 = 0.f;
    for (int k = 0; k < cnt8; k += 8) {
        int4 ra = row[k >> 2];
        int4 rb = row[(k >> 2) + 1];
        float v0 = h[(long)ra.x * hstride + d];
        float v1 = h[(long)ra.y * hstride + d];
        float v2 = h[(long)ra.z * hstride + d];
        float v3 = h[(long)ra.w * hstride + d];
        float v4 = h[(long)rb.x * hstride + d];
        float v5 = h[(long)rb.y * hstride + d];
        float v6 = h[(long)rb.z * hstride + d];
        float v7 = h[(long)rb.w * hstride + d];
        if (k + 0 < cnt) a0 += v0;
        if (k + 1 < cnt) a1 += v1;
        if (k + 2 < cnt) a2 += v2;
        if (k + 3 < cnt) a3 += v3;
        if (k + 4 < cnt) a4 += v4;
        if (k + 5 < cnt) a5 += v5;
        if (k + 6 < cnt) a6 += v6;
        if (k + 7 < cnt) a7 += v7;
    }
    if (dval > CSR_CAP) {  // rare (~1e-4 of nodes)
        int m = min(*ovcnt, OV_CAP);
        for (int i = 0; i < m; ++i) {
            if (ovpairs[2 * i] == n) a0 += h[(long)ovpairs[2 * i + 1] * hstride + d];
        }
    }
    agg[(long)n * DIM + d] = ((a0 + a1) + (a2 + a3)) + ((a4 + a5) + (a6 + a7));
}

// ---------------------------------------------------------------------------
// Fused MLP: z = relu( relu((h+agg)@W1+b1) @ W2 + b2 ), plus per-block BN
// partial sums (sum, sumsq per dim) computed from registers via shfl_xor
// butterflies. One thread per node; acc1/acc2 statically indexed (no scratch).
// ---------------------------------------------------------------------------
__global__ __launch_bounds__(256) void mlp_fused_kernel(
        const float* __restrict__ in, int in_stride, const float* __restrict__ agg,
        const float* __restrict__ W1, const float* __restrict__ b1,
        const float* __restrict__ W2, const float* __restrict__ b2,
        float* __restrict__ z, float* __restrict__ partials) {
    __shared__ __align__(16) float sW1[DIM * DIM];
    __shared__ __align__(16) float sW2[DIM * DIM];
    __shared__ float sb1[DIM], sb2[DIM];
    __shared__ float red[4][2][DIM];
    for (int k = threadIdx.x; k < DIM * DIM / 4; k += 256) {
        ((float4*)sW1)[k] = ((const float4*)W1)[k];
        ((float4*)sW2)[k] = ((const float4*)W2)[k];
    }
    if (threadIdx.x < DIM) { sb1[threadIdx.x] = b1[threadIdx.x]; sb2[threadIdx.x] = b2[threadIdx.x]; }
    __syncthreads();

    int n = blockIdx.x * 256 + threadIdx.x;
    bool valid = n < N_NODES;

    float acc1[DIM];
    float acc2[DIM];
#pragma unroll
    for (int j = 0; j < DIM; ++j) acc1[j] = sb1[j];
#pragma unroll
    for (int j = 0; j < DIM; ++j) acc2[j] = valid ? sb2[j] : 0.f;

    if (valid) {
        const float* inr = in + (long)n * in_stride;
        const float* ar  = agg + (long)n * DIM;
        // Phase A: acc1 = (h+agg) @ W1 + b1
        for (int d4 = 0; d4 < DIM / 4; ++d4) {
            float4 zv = ((const float4*)inr)[d4];
            float4 g  = ((const float4*)ar)[d4];
            zv.x += g.x; zv.y += g.y; zv.z += g.z; zv.w += g.w;
            const float* w0 = sW1 + (d4 * 4 + 0) * DIM;
            const float* w1 = sW1 + (d4 * 4 + 1) * DIM;
            const float* w2 = sW1 + (d4 * 4 + 2) * DIM;
            const float* w3 = sW1 + (d4 * 4 + 3) * DIM;
#pragma unroll
            for (int j = 0; j < DIM; j += 4) {
                float4 a0 = *(const float4*)(w0 + j);
                float4 a1 = *(const float4*)(w1 + j);
                float4 a2 = *(const float4*)(w2 + j);
                float4 a3 = *(const float4*)(w3 + j);
                acc1[j + 0] += zv.x * a0.x + zv.y * a1.x + zv.z * a2.x + zv.w * a3.x;
                acc1[j + 1] += zv.x * a0.y + zv.y * a1.y + zv.z * a2.y + zv.w * a3.y;
                acc1[j + 2] += zv.x * a0.z + zv.y * a1.z + zv.z * a2.z + zv.w * a3.z;
                acc1[j + 3] += zv.x * a0.w + zv.y * a1.w + zv.z * a2.w + zv.w * a3.w;
            }
        }
        // Phase B: acc2 = relu(acc1) @ W2 + b2  (k statically unrolled)
#pragma unroll
        for (int k4 = 0; k4 < DIM / 4; ++k4) {
            float h0 = fmaxf(acc1[4 * k4 + 0], 0.f);
            float h1 = fmaxf(acc1[4 * k4 + 1], 0.f);
            float h2 = fmaxf(acc1[4 * k4 + 2], 0.f);
            float h3 = fmaxf(acc1[4 * k4 + 3], 0.f);
            const float* w0 = sW2 + (4 * k4 + 0) * DIM;
            const float* w1 = sW2 + (4 * k4 + 1) * DIM;
            const float* w2 = sW2 + (4 * k4 + 2) * DIM;
            const float* w3 = sW2 + (4 * k4 + 3) * DIM;
#pragma unroll
            for (int j = 0; j < DIM; j += 4) {
                float4 a0 = *(const float4*)(w0 + j);
                float4 a1 = *(const float4*)(w1 + j);
                float4 a2 = *(const float4*)(w2 + j);
                float4 a3 = *(const float4*)(w3 + j);
                acc2[j + 0] += h0 * a0.x + h1 * a1.x + h2 * a2.x + h3 * a3.x;
                acc2[j + 1] += h0 * a0.y + h1 * a1.y + h2 * a2.y + h3 * a3.y;
                acc2[j + 2] += h0 * a0.z + h1 * a1.z + h2 * a2.z + h3 * a3.z;
                acc2[j + 3] += h0 * a0.w + h1 * a1.w + h2 * a2.w + h3 * a3.w;
            }
        }
    }

    // Outer ReLU (invalid threads stay 0), store z
#pragma unroll
    for (int j = 0; j < DIM; ++j) acc2[j] = fmaxf(acc2[j], 0.f);
    if (valid) {
        float* o = z + (long)n * DIM;
#pragma unroll
        for (int j = 0; j < DIM; j += 4) {
            float4 v = { acc2[j], acc2[j + 1], acc2[j + 2], acc2[j + 3] };
            *(float4*)(o + j) = v;
        }
    }

    // BN partial stats from registers: butterfly per dim; lane j keeps dim j.
    int lane = threadIdx.x & 63;
    int wv = threadIdx.x >> 6;
    float p1 = 0.f, p2 = 0.f;
#pragma unroll
    for (int j = 0; j < DIM; ++j) {
        float v1 = acc2[j];
        float v2 = v1 * v1;
#pragma unroll
        for (int s = 1; s < 64; s <<= 1) {
            v1 += __shfl_xor(v1, s, 64);
            v2 += __shfl_xor(v2, s, 64);
        }
        if (lane == j) { p1 = v1; p2 = v2; }
    }
    red[wv][0][lane] = p1;
    red[wv][1][lane] = p2;
    __syncthreads();
    if (threadIdx.x < 128) {
        int which = threadIdx.x >> 6;
        int dd = threadIdx.x & 63;
        float s = red[0][which][dd] + red[1][which][dd] + red[2][which][dd] + red[3][which][dd];
        partials[blockIdx.x * 128 + which * 64 + dd] = s;
    }
}

__global__ void stats_finalize_kernel(const float* __restrict__ partials,
                                      const float* __restrict__ gamma,
                                      const float* __restrict__ beta,
                                      float* __restrict__ ss) {
    __shared__ float r1[256], r2[256];
    int d = threadIdx.x & 63, q = threadIdx.x >> 6;  // q = 0..3
    float s1 = 0.f, s2 = 0.f;
    for (int b = q; b < NBLK; b += 4) {
        s1 += partials[b * 128 + d];
        s2 += partials[b * 128 + 64 + d];
    }
    r1[threadIdx.x] = s1;
    r2[threadIdx.x] = s2;
    __syncthreads();
    if (threadIdx.x < 64) {
        s1 = r1[d] + r1[64 + d] + r1[128 + d] + r1[192 + d];
        s2 = r2[d] + r2[64 + d] + r2[128 + d] + r2[192 + d];
        float mu = s1 * (1.f / N_NODES);
        float var = s2 * (1.f / N_NODES) - mu * mu;
        float rs = 1.f / sqrtf(fmaxf(var, 0.f) + BN_EPS);
        float sc = gamma[d] * rs;
        ss[d] = sc;
        ss[64 + d] = beta[d] - mu * sc;
    }
}

// z_bn = z*scale + shift, float4-vectorized, written into xs slice (stride 320).
__global__ void bn_apply_kernel(const float* __restrict__ z, const float* __restrict__ ss,
                                float* __restrict__ outxs) {
    long t = (long)blockIdx.x * 256 + threadIdx.x;
    if (t >= (long)N_NODES * (DIM / 4)) return;
    int r = (int)(t & 15);
    long n = t >> 4;
    float4 v = ((const float4*)(z + n * DIM))[r];
    float4 sc = ((const float4*)ss)[r];
    float4 sh = ((const float4*)(ss + DIM))[r];
    float4 o = { v.x * sc.x + sh.x, v.y * sc.y + sh.y,
                 v.z * sc.z + sh.z, v.w * sc.w + sh.w };
    ((float4*)(outxs + n * (DIM * NLAYERS)))[r] = o;
}

// batch is sorted: segment starts via binary search.
__global__ void graph_starts_kernel(const int* __restrict__ batch, int* __restrict__ starts) {
    int g = threadIdx.x;
    if (g > NUM_GRAPHS) return;
    int lo = 0, hi = N_NODES;
    while (lo < hi) {
        int mid = (lo + hi) >> 1;
        if (batch[mid] < g) lo = mid + 1; else hi = mid;
    }
    starts[g] = lo;
}

// Pool: block = graph, 320 threads = dims; unrolled x8 over nodes.
__global__ void pool_kernel(const float* __restrict__ xs, const int* __restrict__ starts,
                            float* __restrict__ outpool) {
    int g = blockIdx.x;
    int d = threadIdx.x;
    int s = starts[g], e = starts[g + 1];
    const int LD = DIM * NLAYERS;
    float a0 = 0.f, a1 = 0.f, a2 = 0.f, a3 = 0.f;
    float a4 = 0.f, a5 = 0.f, a6 = 0.f, a7 = 0.f;
    int n = s;
    for (; n + 8 <= e; n += 8) {
        a0 += xs[(long)(n + 0) * LD + d];
        a1 += xs[(long)(n + 1) * LD + d];
        a2 += xs[(long)(n + 2) * LD + d];
        a3 += xs[(long)(n + 3) * LD + d];
        a4 += xs[(long)(n + 4) * LD + d];
        a5 += xs[(long)(n + 5) * LD + d];
        a6 += xs[(long)(n + 6) * LD + d];
        a7 += xs[(long)(n + 7) * LD + d];
    }
    for (; n < e; ++n) a0 += xs[(long)n * LD + d];
    float acc = ((a0 + a1) + (a2 + a3)) + ((a4 + a5) + (a6 + a7));
    outpool[(long)g * LD + d] = acc / fmaxf((float)(e - s), 1.f);
}

// ---------------------------------------------------------------------------
static inline size_t rup(size_t x) { return (x + 255) & ~(size_t)255; }

extern "C" void kernel_launch(void* const* d_in, const int* in_sizes, int n_in,
                              void* d_out, int out_size, void* d_ws, size_t ws_size,
                              hipStream_t stream) {
    const float* x     = (const float*)d_in[0];
    const int*   ei    = (const int*)d_in[1];
    const int*   batch = (const int*)d_in[2];
    const float* W1    = (const float*)d_in[3];
    const float* b1    = (const float*)d_in[4];
    const float* W2    = (const float*)d_in[5];
    const float* b2    = (const float*)d_in[6];
    const float* gamma = (const float*)d_in[7];
    const float* beta  = (const float*)d_in[8];

    float* out      = (float*)d_out;
    float* out_pool = out;                                      // 256 x 320
    float* out_xs   = out + (size_t)NUM_GRAPHS * DIM * NLAYERS; // 100000 x 320

    char* w = (char*)d_ws;
    int*   csr      = (int*)w;    w += rup((size_t)N_NODES * CSR_CAP * 4);
    int*   cursor   = (int*)w;    w += rup((size_t)N_NODES * 4);
    int*   ovcnt    = (int*)w;    w += 256;
    int*   ovpairs  = (int*)w;    w += rup((size_t)OV_CAP * 8);
    float* agg      = (float*)w;  w += rup((size_t)N_NODES * DIM * 4);
    float* bufB     = (float*)w;  w += rup((size_t)N_NODES * DIM * 4);
    float* partials = (float*)w;  w += rup((size_t)NBLK * 128 * 4);
    float* ss       = (float*)w;  w += 512;
    int*   starts   = (int*)w;    w += rup((size_t)(NUM_GRAPHS + 1) * 4);

    hipMemsetAsync(cursor, 0, (size_t)N_NODES * 4, stream);
    hipMemsetAsync(ovcnt, 0, 4, stream);
    build_csr_kernel<<<(N_EDGES / 4 + 255) / 256, 256, 0, stream>>>(ei, cursor, csr, ovcnt, ovpairs);
    pad_csr_kernel<<<NBLK, 256, 0, stream>>>(cursor, csr);
    graph_starts_kernel<<<1, 320, 0, stream>>>(batch, starts);

    const float* h = x;
    int hs = DIM;
    for (int l = 0; l < NLAYERS; ++l) {
        aggregate_kernel<<<((long)N_NODES * DIM + 255) / 256, 256, 0, stream>>>(
            csr, cursor, ovcnt, ovpairs, h, hs, agg);
        mlp_fused_kernel<<<NBLK, 256, 0, stream>>>(
            h, hs, agg,
            W1 + (size_t)l * DIM * DIM, b1 + (size_t)l * DIM,
            W2 + (size_t)l * DIM * DIM, b2 + (size_t)l * DIM,
            bufB, partials);
        stats_finalize_kernel<<<1, 256, 0, stream>>>(partials, gamma + (size_t)l * DIM,
                                                     beta + (size_t)l * DIM, ss);
        bn_apply_kernel<<<((long)N_NODES * (DIM / 4) + 255) / 256, 256, 0, stream>>>(
            bufB, ss, out_xs + (size_t)l * DIM);
        h = out_xs + (size_t)l * DIM;
        hs = DIM * NLAYERS;
    }

    pool_kernel<<<NUM_GRAPHS, 320, 0, stream>>>(out_xs, starts, out_pool);
}

// Round 4
// 984.234 us; speedup vs baseline: 1.8238x; 1.8238x over previous
//
#include <hip/hip_runtime.h>

#define N_NODES 100000
#define N_EDGES 1600000
#define DIM 64
#define NLAYERS 5
#define NUM_GRAPHS 256
#define BN_EPS 1e-5f
#define STATS_BLOCKS 256
#define CSR_CAP 32
#define OV_CAP 65536
#define NBLK ((N_NODES + 255) / 256)   /* 391 */

// ---------------------------------------------------------------------------
// CSR build, 4 edges/thread: 4 atomic round-trips in flight (latency-bound).
// cursor zeroed before; ends as true in-degree. Overflow -> (t,s) pair list.
// ---------------------------------------------------------------------------
__global__ __launch_bounds__(256) void build_csr_kernel(
        const int* __restrict__ ei, int* __restrict__ cursor,
        int* __restrict__ csr, int* __restrict__ ovcnt, int* __restrict__ ovpairs) {
    const int Q = N_EDGES / 4;  // 400000
    int tid = blockIdx.x * 256 + threadIdx.x;
    if (tid >= Q) return;
    int e0 = tid, e1 = tid + Q, e2 = tid + 2 * Q, e3 = tid + 3 * Q;
    int s0 = ei[e0], s1 = ei[e1], s2 = ei[e2], s3 = ei[e3];
    int t0 = ei[N_EDGES + e0], t1 = ei[N_EDGES + e1];
    int t2 = ei[N_EDGES + e2], t3 = ei[N_EDGES + e3];
    int c0 = atomicAdd(&cursor[t0], 1);
    int c1 = atomicAdd(&cursor[t1], 1);
    int c2 = atomicAdd(&cursor[t2], 1);
    int c3 = atomicAdd(&cursor[t3], 1);
    if (c0 < CSR_CAP) csr[t0 * CSR_CAP + c0] = s0;
    else { int o = atomicAdd(ovcnt, 1); if (o < OV_CAP) { ovpairs[2*o] = t0; ovpairs[2*o+1] = s0; } }
    if (c1 < CSR_CAP) csr[t1 * CSR_CAP + c1] = s1;
    else { int o = atomicAdd(ovcnt, 1); if (o < OV_CAP) { ovpairs[2*o] = t1; ovpairs[2*o+1] = s1; } }
    if (c2 < CSR_CAP) csr[t2 * CSR_CAP + c2] = s2;
    else { int o = atomicAdd(ovcnt, 1); if (o < OV_CAP) { ovpairs[2*o] = t2; ovpairs[2*o+1] = s2; } }
    if (c3 < CSR_CAP) csr[t3 * CSR_CAP + c3] = s3;
    else { int o = atomicAdd(ovcnt, 1); if (o < OV_CAP) { ovpairs[2*o] = t3; ovpairs[2*o+1] = s3; } }
}

__global__ void pad_csr_kernel(const int* __restrict__ cursor, int* __restrict__ csr) {
    int n = blockIdx.x * 256 + threadIdx.x;
    if (n >= N_NODES) return;
    int cnt = min(cursor[n], CSR_CAP);
    int cnt8 = (cnt + 7) & ~7;
    for (int k = cnt; k < cnt8; ++k) csr[n * CSR_CAP + k] = 0;
}

// ---------------------------------------------------------------------------
// Aggregate + self: z0[n] = h[n] + sum_{j->n} h[j]. Wave = node, lane = dim;
// 8 independent 256B gathers in flight; wave-uniform predication.
// ---------------------------------------------------------------------------
__global__ __launch_bounds__(256) void aggregate_kernel(
        const int* __restrict__ csr, const int* __restrict__ deg,
        const int* __restrict__ ovcnt, const int* __restrict__ ovpairs,
        const float* __restrict__ h, int hstride, float* __restrict__ agg) {
    long tid = (long)blockIdx.x * 256 + threadIdx.x;
    int n = (int)(tid >> 6);
    int d = (int)(tid & 63);
    if (n >= N_NODES) return;
    int dval = deg[n];
    int cnt = min(dval, CSR_CAP);
    int cnt8 = (cnt + 7) & ~7;
    const int4* row = (const int4*)(csr + n * CSR_CAP);  // 128B-aligned
    float own = h[(long)n * hstride + d];
    float a0 = 0.f, a1 = 0.f, a2 = 0.f, a3 = 0.f;
    float a4 = 0.f, a5 = 0.f, a6 = 0.f, a7 = 0.f;
    for (int k = 0; k < cnt8; k += 8) {
        int4 ra = row[k >> 2];
        int4 rb = row[(k >> 2) + 1];
        float v0 = h[(long)ra.x * hstride + d];
        float v1 = h[(long)ra.y * hstride + d];
        float v2 = h[(long)ra.z * hstride + d];
        float v3 = h[(long)ra.w * hstride + d];
        float v4 = h[(long)rb.x * hstride + d];
        float v5 = h[(long)rb.y * hstride + d];
        float v6 = h[(long)rb.z * hstride + d];
        float v7 = h[(long)rb.w * hstride + d];
        if (k + 0 < cnt) a0 += v0;
        if (k + 1 < cnt) a1 += v1;
        if (k + 2 < cnt) a2 += v2;
        if (k + 3 < cnt) a3 += v3;
        if (k + 4 < cnt) a4 += v4;
        if (k + 5 < cnt) a5 += v5;
        if (k + 6 < cnt) a6 += v6;
        if (k + 7 < cnt) a7 += v7;
    }
    if (dval > CSR_CAP) {  // rare
        int m = min(*ovcnt, OV_CAP);
        for (int i = 0; i < m; ++i) {
            if (ovpairs[2 * i] == n) a0 += h[(long)ovpairs[2 * i + 1] * hstride + d];
        }
    }
    agg[(long)n * DIM + d] = own + ((a0 + a1) + (a2 + a3)) + ((a4 + a5) + (a6 + a7));
}

// ---------------------------------------------------------------------------
// out[n] = relu(in[n] @ W + b). 2 nodes x 32 dims per thread: same FMA count,
// half the ds_read_b128 per FMA (LDS-issue was the gemm bottleneck).
// Block = 256 nodes: p = tid&127 -> nodes (base+p, base+128+p);
// half = tid>>7 -> output dims [half*32, half*32+32).
// All sW reads are wave-uniform (broadcast, conflict-free). ~105 VGPR.
// ---------------------------------------------------------------------------
__global__ __launch_bounds__(256) void mlp_gemm_kernel(
        const float* __restrict__ in, const float* __restrict__ W,
        const float* __restrict__ b, float* __restrict__ out) {
    __shared__ __align__(16) float sW[DIM * DIM];
    __shared__ float sb[DIM];
    for (int k = threadIdx.x; k < DIM * DIM / 4; k += 256)
        ((float4*)sW)[k] = ((const float4*)W)[k];
    if (threadIdx.x < DIM) sb[threadIdx.x] = b[threadIdx.x];
    __syncthreads();

    int p = threadIdx.x & 127;
    int j0 = (threadIdx.x >> 7) * 32;
    int base = blockIdx.x * 256;
    int n0 = base + p;            // always < N_NODES for our grid
    int n1 = base + 128 + p;
    bool v1 = n1 < N_NODES;
    const float* inr0 = in + (long)n0 * DIM;
    const float* inr1 = in + (long)(v1 ? n1 : n0) * DIM;

    float acc0[32], acc1[32];
#pragma unroll
    for (int j = 0; j < 32; ++j) { acc0[j] = sb[j0 + j]; acc1[j] = acc0[j]; }

    for (int d4 = 0; d4 < DIM / 4; ++d4) {
        float4 za = ((const float4*)inr0)[d4];
        float4 zb = ((const float4*)inr1)[d4];
        const float* w0 = sW + (d4 * 4 + 0) * DIM + j0;
        const float* w1 = sW + (d4 * 4 + 1) * DIM + j0;
        const float* w2 = sW + (d4 * 4 + 2) * DIM + j0;
        const float* w3 = sW + (d4 * 4 + 3) * DIM + j0;
#pragma unroll
        for (int j = 0; j < 32; j += 4) {
            float4 a0 = *(const float4*)(w0 + j);
            float4 a1 = *(const float4*)(w1 + j);
            float4 a2 = *(const float4*)(w2 + j);
            float4 a3 = *(const float4*)(w3 + j);
            acc0[j + 0] += za.x * a0.x + za.y * a1.x + za.z * a2.x + za.w * a3.x;
            acc0[j + 1] += za.x * a0.y + za.y * a1.y + za.z * a2.y + za.w * a3.y;
            acc0[j + 2] += za.x * a0.z + za.y * a1.z + za.z * a2.z + za.w * a3.z;
            acc0[j + 3] += za.x * a0.w + za.y * a1.w + za.z * a2.w + za.w * a3.w;
            acc1[j + 0] += zb.x * a0.x + zb.y * a1.x + zb.z * a2.x + zb.w * a3.x;
            acc1[j + 1] += zb.x * a0.y + zb.y * a1.y + zb.z * a2.y + zb.w * a3.y;
            acc1[j + 2] += zb.x * a0.z + zb.y * a1.z + zb.z * a2.z + zb.w * a3.z;
            acc1[j + 3] += zb.x * a0.w + zb.y * a1.w + zb.z * a2.w + zb.w * a3.w;
        }
    }

    float* o0 = out + (long)n0 * DIM + j0;
#pragma unroll
    for (int j = 0; j < 32; j += 4) {
        float4 v = { fmaxf(acc0[j], 0.f), fmaxf(acc0[j + 1], 0.f),
                     fmaxf(acc0[j + 2], 0.f), fmaxf(acc0[j + 3], 0.f) };
        *(float4*)(o0 + j) = v;
    }
    if (v1) {
        float* o1 = out + (long)n1 * DIM + j0;
#pragma unroll
        for (int j = 0; j < 32; j += 4) {
            float4 v = { fmaxf(acc1[j], 0.f), fmaxf(acc1[j + 1], 0.f),
                         fmaxf(acc1[j + 2], 0.f), fmaxf(acc1[j + 3], 0.f) };
            *(float4*)(o1 + j) = v;
        }
    }
}

// ---------------------------------------------------------------------------
// BN stats: per-block partial (sum, sumsq) per dim, unrolled x4; finalize.
// ---------------------------------------------------------------------------
__global__ void stats_partial_kernel(const float* __restrict__ z, float* __restrict__ partials) {
    __shared__ float red[2 * 256];
    int d = threadIdx.x & 63;
    int slot = threadIdx.x >> 6;
    const int S = STATS_BLOCKS * 4;  // 1024
    float s1 = 0.f, s2 = 0.f;
    int n = blockIdx.x * 4 + slot;
    for (; n + 3 * S < N_NODES; n += 4 * S) {
        float v0 = z[(long)(n + 0 * S) * DIM + d];
        float v1 = z[(long)(n + 1 * S) * DIM + d];
        float v2 = z[(long)(n + 2 * S) * DIM + d];
        float v3 = z[(long)(n + 3 * S) * DIM + d];
        s1 += v0 + v1 + v2 + v3;
        s2 += v0 * v0 + v1 * v1 + v2 * v2 + v3 * v3;
    }
    for (; n < N_NODES; n += S) {
        float v = z[(long)n * DIM + d];
        s1 += v;
        s2 += v * v;
    }
    red[threadIdx.x] = s1;
    red[256 + threadIdx.x] = s2;
    __syncthreads();
    if (threadIdx.x < 64) {
        float a = red[d] + red[64 + d] + red[128 + d] + red[192 + d];
        float c = red[256 + d] + red[320 + d] + red[384 + d] + red[448 + d];
        partials[blockIdx.x * 128 + d] = a;
        partials[blockIdx.x * 128 + 64 + d] = c;
    }
}

__global__ void stats_finalize_kernel(const float* __restrict__ partials,
                                      const float* __restrict__ gamma,
                                      const float* __restrict__ beta,
                                      float* __restrict__ ss) {
    __shared__ float r1[256], r2[256];
    int d = threadIdx.x & 63, q = threadIdx.x >> 6;
    float s1 = 0.f, s2 = 0.f;
    for (int b2_ = q; b2_ < STATS_BLOCKS; b2_ += 4) {
        s1 += partials[b2_ * 128 + d];
        s2 += partials[b2_ * 128 + 64 + d];
    }
    r1[threadIdx.x] = s1;
    r2[threadIdx.x] = s2;
    __syncthreads();
    if (threadIdx.x < 64) {
        s1 = r1[d] + r1[64 + d] + r1[128 + d] + r1[192 + d];
        s2 = r2[d] + r2[64 + d] + r2[128 + d] + r2[192 + d];
        float mu = s1 * (1.f / N_NODES);
        float var = s2 * (1.f / N_NODES) - mu * mu;
        float rs = 1.f / sqrtf(fmaxf(var, 0.f) + BN_EPS);
        float sc = gamma[d] * rs;
        ss[d] = sc;
        ss[64 + d] = beta[d] - mu * sc;
    }
}

// z_bn = z*scale + shift into xs slice (row stride 320), float4-vectorized.
__global__ void bn_apply_kernel(const float* __restrict__ z, const float* __restrict__ ss,
                                float* __restrict__ outxs) {
    long t = (long)blockIdx.x * 256 + threadIdx.x;
    if (t >= (long)N_NODES * (DIM / 4)) return;
    int r = (int)(t & 15);
    long n = t >> 4;
    float4 v = ((const float4*)(z + n * DIM))[r];
    float4 sc = ((const float4*)ss)[r];
    float4 sh = ((const float4*)(ss + DIM))[r];
    float4 o = { v.x * sc.x + sh.x, v.y * sc.y + sh.y,
                 v.z * sc.z + sh.z, v.w * sc.w + sh.w };
    ((float4*)(outxs + n * (DIM * NLAYERS)))[r] = o;
}

__global__ void graph_starts_kernel(const int* __restrict__ batch, int* __restrict__ starts) {
    int g = threadIdx.x;
    if (g > NUM_GRAPHS) return;
    int lo = 0, hi = N_NODES;
    while (lo < hi) {
        int mid = (lo + hi) >> 1;
        if (batch[mid] < g) lo = mid + 1; else hi = mid;
    }
    starts[g] = lo;
}

__global__ void pool_kernel(const float* __restrict__ xs, const int* __restrict__ starts,
                            float* __restrict__ outpool) {
    int g = blockIdx.x;
    int d = threadIdx.x;
    int s = starts[g], e = starts[g + 1];
    const int LD = DIM * NLAYERS;
    float a0 = 0.f, a1 = 0.f, a2 = 0.f, a3 = 0.f;
    float a4 = 0.f, a5 = 0.f, a6 = 0.f, a7 = 0.f;
    int n = s;
    for (; n + 8 <= e; n += 8) {
        a0 += xs[(long)(n + 0) * LD + d];
        a1 += xs[(long)(n + 1) * LD + d];
        a2 += xs[(long)(n + 2) * LD + d];
        a3 += xs[(long)(n + 3) * LD + d];
        a4 += xs[(long)(n + 4) * LD + d];
        a5 += xs[(long)(n + 5) * LD + d];
        a6 += xs[(long)(n + 6) * LD + d];
        a7 += xs[(long)(n + 7) * LD + d];
    }
    for (; n < e; ++n) a0 += xs[(long)n * LD + d];
    float acc = ((a0 + a1) + (a2 + a3)) + ((a4 + a5) + (a6 + a7));
    outpool[(long)g * LD + d] = acc / fmaxf((float)(e - s), 1.f);
}

// ---------------------------------------------------------------------------
static inline size_t rup(size_t x) { return (x + 255) & ~(size_t)255; }

extern "C" void kernel_launch(void* const* d_in, const int* in_sizes, int n_in,
                              void* d_out, int out_size, void* d_ws, size_t ws_size,
                              hipStream_t stream) {
    const float* x     = (const float*)d_in[0];
    const int*   ei    = (const int*)d_in[1];
    const int*   batch = (const int*)d_in[2];
    const float* W1    = (const float*)d_in[3];
    const float* b1    = (const float*)d_in[4];
    const float* W2    = (const float*)d_in[5];
    const float* b2    = (const float*)d_in[6];
    const float* gamma = (const float*)d_in[7];
    const float* beta  = (const float*)d_in[8];

    float* out      = (float*)d_out;
    float* out_pool = out;                                      // 256 x 320
    float* out_xs   = out + (size_t)NUM_GRAPHS * DIM * NLAYERS; // 100000 x 320

    char* w = (char*)d_ws;
    int*   csr      = (int*)w;    w += rup((size_t)N_NODES * CSR_CAP * 4);
    int*   cursor   = (int*)w;    w += rup((size_t)N_NODES * 4);
    int*   ovcnt    = (int*)w;    w += 256;
    int*   ovpairs  = (int*)w;    w += rup((size_t)OV_CAP * 8);
    float* agg      = (float*)w;  w += rup((size_t)N_NODES * DIM * 4);
    float* bufB     = (float*)w;  w += rup((size_t)N_NODES * DIM * 4);
    float* partials = (float*)w;  w += rup((size_t)STATS_BLOCKS * 128 * 4);
    float* ss       = (float*)w;  w += 512;
    int*   starts   = (int*)w;    w += rup((size_t)(NUM_GRAPHS + 1) * 4);

    hipMemsetAsync(cursor, 0, (size_t)N_NODES * 4, stream);
    hipMemsetAsync(ovcnt, 0, 4, stream);
    build_csr_kernel<<<(N_EDGES / 4 + 255) / 256, 256, 0, stream>>>(ei, cursor, csr, ovcnt, ovpairs);
    pad_csr_kernel<<<NBLK, 256, 0, stream>>>(cursor, csr);
    graph_starts_kernel<<<1, 320, 0, stream>>>(batch, starts);

    const float* h = x;
    int hs = DIM;
    for (int l = 0; l < NLAYERS; ++l) {
        // agg = h + neighbor-sum(h)
        aggregate_kernel<<<((long)N_NODES * DIM + 255) / 256, 256, 0, stream>>>(
            csr, cursor, ovcnt, ovpairs, h, hs, agg);
        // bufB = relu(agg @ W1 + b1)
        mlp_gemm_kernel<<<NBLK, 256, 0, stream>>>(
            agg, W1 + (size_t)l * DIM * DIM, b1 + (size_t)l * DIM, bufB);
        // agg (reused) = relu(bufB @ W2 + b2)   [outer ReLU == z]
        mlp_gemm_kernel<<<NBLK, 256, 0, stream>>>(
            bufB, W2 + (size_t)l * DIM * DIM, b2 + (size_t)l * DIM, agg);
        stats_partial_kernel<<<STATS_BLOCKS, 256, 0, stream>>>(agg, partials);
        stats_finalize_kernel<<<1, 256, 0, stream>>>(partials, gamma + (size_t)l * DIM,
                                                     beta + (size_t)l * DIM, ss);
        bn_apply_kernel<<<((long)N_NODES * (DIM / 4) + 255) / 256, 256, 0, stream>>>(
            agg, ss, out_xs + (size_t)l * DIM);
        h = out_xs + (size_t)l * DIM;
        hs = DIM * NLAYERS;
    }

    pool_kernel<<<NUM_GRAPHS, 320, 0, stream>>>(out_xs, starts, out_pool);
}

// Round 6
// 959.976 us; speedup vs baseline: 1.8699x; 1.0253x over previous
//
#include <hip/hip_runtime.h>

#define N_NODES 100000
#define N_EDGES 1600000
#define DIM 64
#define NLAYERS 5
#define NUM_GRAPHS 256
#define BN_EPS 1e-5f
#define STATS_BLOCKS 256
#define CSR_CAP 32
#define OV_CAP 65536
#define NSHARD 4
#define SHARD_W (N_NODES / NSHARD)     /* 25000 */
#define NBLK ((N_NODES + 255) / 256)   /* 391 */

// ---------------------------------------------------------------------------
// CSR build, sharded by target range: 4 sequential passes, each pass only
// writes CSR rows for t in [lo,hi). Dirty footprint per pass = 3.2MB < 4MB
// per-XCD L2, so scattered slot writes merge in L2 before eviction (R4
// showed 96MB WRITE_SIZE = 8-XCD thrash of the full 12.8MB range).
// cursor zeroed before pass 0; ends as true in-degree.
// ---------------------------------------------------------------------------
__global__ __launch_bounds__(256) void build_csr_shard_kernel(
        const int* __restrict__ ei, int* __restrict__ cursor,
        int* __restrict__ csr, int* __restrict__ ovcnt, int* __restrict__ ovpairs,
        int lo, int hi) {
    int e = blockIdx.x * 256 + threadIdx.x;
    if (e >= N_EDGES) return;
    int t = ei[N_EDGES + e];
    if (t < lo || t >= hi) return;
    int s = ei[e];
    int c = atomicAdd(&cursor[t], 1);
    if (c < CSR_CAP) {
        csr[t * CSR_CAP + c] = s;
    } else {
        int o = atomicAdd(ovcnt, 1);
        if (o < OV_CAP) { ovpairs[2 * o] = t; ovpairs[2 * o + 1] = s; }
    }
}

__global__ void pad_csr_kernel(const int* __restrict__ cursor, int* __restrict__ csr) {
    int n = blockIdx.x * 256 + threadIdx.x;
    if (n >= N_NODES) return;
    int cnt = min(cursor[n], CSR_CAP);
    int cnt8 = (cnt + 7) & ~7;
    for (int k = cnt; k < cnt8; ++k) csr[n * CSR_CAP + k] = 0;
}

// ---------------------------------------------------------------------------
// Aggregate + self: agg[n] = h[n] + sum_{j->n} h[j]. Wave = node, lane = dim;
// 8 independent 256B gathers in flight; wave-uniform predication.
// ---------------------------------------------------------------------------
__global__ __launch_bounds__(256) void aggregate_kernel(
        const int* __restrict__ csr, const int* __restrict__ deg,
        const int* __restrict__ ovcnt, const int* __restrict__ ovpairs,
        const float* __restrict__ h, int hstride, float* __restrict__ agg) {
    long tid = (long)blockIdx.x * 256 + threadIdx.x;
    int n = (int)(tid >> 6);
    int d = (int)(tid & 63);
    if (n >= N_NODES) return;
    int dval = deg[n];
    int cnt = min(dval, CSR_CAP);
    int cnt8 = (cnt + 7) & ~7;
    const int4* row = (const int4*)(csr + n * CSR_CAP);  // 128B-aligned
    float own = h[(long)n * hstride + d];
    float a0 = 0.f, a1 = 0.f, a2 = 0.f, a3 = 0.f;
    float a4 = 0.f, a5 = 0.f, a6 = 0.f, a7 = 0.f;
    for (int k = 0; k < cnt8; k += 8) {
        int4 ra = row[k >> 2];
        int4 rb = row[(k >> 2) + 1];
        float v0 = h[(long)ra.x * hstride + d];
        float v1 = h[(long)ra.y * hstride + d];
        float v2 = h[(long)ra.z * hstride + d];
        float v3 = h[(long)ra.w * hstride + d];
        float v4 = h[(long)rb.x * hstride + d];
        float v5 = h[(long)rb.y * hstride + d];
        float v6 = h[(long)rb.z * hstride + d];
        float v7 = h[(long)rb.w * hstride + d];
        if (k + 0 < cnt) a0 += v0;
        if (k + 1 < cnt) a1 += v1;
        if (k + 2 < cnt) a2 += v2;
        if (k + 3 < cnt) a3 += v3;
        if (k + 4 < cnt) a4 += v4;
        if (k + 5 < cnt) a5 += v5;
        if (k + 6 < cnt) a6 += v6;
        if (k + 7 < cnt) a7 += v7;
    }
    if (dval > CSR_CAP) {  // rare
        int m = min(*ovcnt, OV_CAP);
        for (int i = 0; i < m; ++i) {
            if (ovpairs[2 * i] == n) a0 += h[(long)ovpairs[2 * i + 1] * hstride + d];
        }
    }
    agg[(long)n * DIM + d] = own + ((a0 + a1) + (a2 + a3)) + ((a4 + a5) + (a6 + a7));
}

// ---------------------------------------------------------------------------
// out[n] = relu(in[n] @ W + b). 2 nodes x 32 dims per thread (half the
// ds_read_b128 per FMA). All sW reads wave-uniform (broadcast).
// ---------------------------------------------------------------------------
__global__ __launch_bounds__(256) void mlp_gemm_kernel(
        const float* __restrict__ in, const float* __restrict__ W,
        const float* __restrict__ b, float* __restrict__ out) {
    __shared__ __align__(16) float sW[DIM * DIM];
    __shared__ float sb[DIM];
    for (int k = threadIdx.x; k < DIM * DIM / 4; k += 256)
        ((float4*)sW)[k] = ((const float4*)W)[k];
    if (threadIdx.x < DIM) sb[threadIdx.x] = b[threadIdx.x];
    __syncthreads();

    int p = threadIdx.x & 127;
    int j0 = (threadIdx.x >> 7) * 32;
    int base = blockIdx.x * 256;
    int n0 = base + p;
    int n1 = base + 128 + p;
    bool v1 = n1 < N_NODES;
    const float* inr0 = in + (long)n0 * DIM;
    const float* inr1 = in + (long)(v1 ? n1 : n0) * DIM;

    float acc0[32], acc1[32];
#pragma unroll
    for (int j = 0; j < 32; ++j) { acc0[j] = sb[j0 + j]; acc1[j] = acc0[j]; }

    for (int d4 = 0; d4 < DIM / 4; ++d4) {
        float4 za = ((const float4*)inr0)[d4];
        float4 zb = ((const float4*)inr1)[d4];
        const float* w0 = sW + (d4 * 4 + 0) * DIM + j0;
        const float* w1 = sW + (d4 * 4 + 1) * DIM + j0;
        const float* w2 = sW + (d4 * 4 + 2) * DIM + j0;
        const float* w3 = sW + (d4 * 4 + 3) * DIM + j0;
#pragma unroll
        for (int j = 0; j < 32; j += 4) {
            float4 a0 = *(const float4*)(w0 + j);
            float4 a1 = *(const float4*)(w1 + j);
            float4 a2 = *(const float4*)(w2 + j);
            float4 a3 = *(const float4*)(w3 + j);
            acc0[j + 0] += za.x * a0.x + za.y * a1.x + za.z * a2.x + za.w * a3.x;
            acc0[j + 1] += za.x * a0.y + za.y * a1.y + za.z * a2.y + za.w * a3.y;
            acc0[j + 2] += za.x * a0.z + za.y * a1.z + za.z * a2.z + za.w * a3.z;
            acc0[j + 3] += za.x * a0.w + za.y * a1.w + za.z * a2.w + za.w * a3.w;
            acc1[j + 0] += zb.x * a0.x + zb.y * a1.x + zb.z * a2.x + zb.w * a3.x;
            acc1[j + 1] += zb.x * a0.y + zb.y * a1.y + zb.z * a2.y + zb.w * a3.y;
            acc1[j + 2] += zb.x * a0.z + zb.y * a1.z + zb.z * a2.z + zb.w * a3.z;
            acc1[j + 3] += zb.x * a0.w + zb.y * a1.w + zb.z * a2.w + zb.w * a3.w;
        }
    }

    float* o0 = out + (long)n0 * DIM + j0;
#pragma unroll
    for (int j = 0; j < 32; j += 4) {
        float4 v = { fmaxf(acc0[j], 0.f), fmaxf(acc0[j + 1], 0.f),
                     fmaxf(acc0[j + 2], 0.f), fmaxf(acc0[j + 3], 0.f) };
        *(float4*)(o0 + j) = v;
    }
    if (v1) {
        float* o1 = out + (long)n1 * DIM + j0;
#pragma unroll
        for (int j = 0; j < 32; j += 4) {
            float4 v = { fmaxf(acc1[j], 0.f), fmaxf(acc1[j + 1], 0.f),
                         fmaxf(acc1[j + 2], 0.f), fmaxf(acc1[j + 3], 0.f) };
            *(float4*)(o1 + j) = v;
        }
    }
}

// ---------------------------------------------------------------------------
// BN stats: per-block partial (sum, sumsq) per dim, unrolled x4; finalize.
// ---------------------------------------------------------------------------
__global__ void stats_partial_kernel(const float* __restrict__ z, float* __restrict__ partials) {
    __shared__ float red[2 * 256];
    int d = threadIdx.x & 63;
    int slot = threadIdx.x >> 6;
    const int S = STATS_BLOCKS * 4;  // 1024
    float s1 = 0.f, s2 = 0.f;
    int n = blockIdx.x * 4 + slot;
    for (; n + 3 * S < N_NODES; n += 4 * S) {
        float v0 = z[(long)(n + 0 * S) * DIM + d];
        float v1 = z[(long)(n + 1 * S) * DIM + d];
        float v2 = z[(long)(n + 2 * S) * DIM + d];
        float v3 = z[(long)(n + 3 * S) * DIM + d];
        s1 += v0 + v1 + v2 + v3;
        s2 += v0 * v0 + v1 * v1 + v2 * v2 + v3 * v3;
    }
    for (; n < N_NODES; n += S) {
        float v = z[(long)n * DIM + d];
        s1 += v;
        s2 += v * v;
    }
    red[threadIdx.x] = s1;
    red[256 + threadIdx.x] = s2;
    __syncthreads();
    if (threadIdx.x < 64) {
        float a = red[d] + red[64 + d] + red[128 + d] + red[192 + d];
        float c = red[256 + d] + red[320 + d] + red[384 + d] + red[448 + d];
        partials[blockIdx.x * 128 + d] = a;
        partials[blockIdx.x * 128 + 64 + d] = c;
    }
}

__global__ void stats_finalize_kernel(const float* __restrict__ partials,
                                      const float* __restrict__ gamma,
                                      const float* __restrict__ beta,
                                      float* __restrict__ ss) {
    __shared__ float r1[256], r2[256];
    int d = threadIdx.x & 63, q = threadIdx.x >> 6;
    float s1 = 0.f, s2 = 0.f;
    for (int b2_ = q; b2_ < STATS_BLOCKS; b2_ += 4) {
        s1 += partials[b2_ * 128 + d];
        s2 += partials[b2_ * 128 + 64 + d];
    }
    r1[threadIdx.x] = s1;
    r2[threadIdx.x] = s2;
    __syncthreads();
    if (threadIdx.x < 64) {
        s1 = r1[d] + r1[64 + d] + r1[128 + d] + r1[192 + d];
        s2 = r2[d] + r2[64 + d] + r2[128 + d] + r2[192 + d];
        float mu = s1 * (1.f / N_NODES);
        float var = s2 * (1.f / N_NODES) - mu * mu;
        float rs = 1.f / sqrtf(fmaxf(var, 0.f) + BN_EPS);
        float sc = gamma[d] * rs;
        ss[d] = sc;
        ss[64 + d] = beta[d] - mu * sc;
    }
}

// z_bn = z*scale + shift into xs slice (row stride 320), float4-vectorized.
__global__ void bn_apply_kernel(const float* __restrict__ z, const float* __restrict__ ss,
                                float* __restrict__ outxs) {
    long t = (long)blockIdx.x * 256 + threadIdx.x;
    if (t >= (long)N_NODES * (DIM / 4)) return;
    int r = (int)(t & 15);
    long n = t >> 4;
    float4 v = ((const float4*)(z + n * DIM))[r];
    float4 sc = ((const float4*)ss)[r];
    float4 sh = ((const float4*)(ss + DIM))[r];
    float4 o = { v.x * sc.x + sh.x, v.y * sc.y + sh.y,
                 v.z * sc.z + sh.z, v.w * sc.w + sh.w };
    ((float4*)(outxs + n * (DIM * NLAYERS)))[r] = o;
}

__global__ void graph_starts_kernel(const int* __restrict__ batch, int* __restrict__ starts) {
    int g = threadIdx.x;
    if (g > NUM_GRAPHS) return;
    int lo = 0, hi = N_NODES;
    while (lo < hi) {
        int mid = (lo + hi) >> 1;
        if (batch[mid] < g) lo = mid + 1; else hi = mid;
    }
    starts[g] = lo;
}

__global__ void pool_kernel(const float* __restrict__ xs, const int* __restrict__ starts,
                            float* __restrict__ outpool) {
    int g = blockIdx.x;
    int d = threadIdx.x;
    int s = starts[g], e = starts[g + 1];
    const int LD = DIM * NLAYERS;
    float a0 = 0.f, a1 = 0.f, a2 = 0.f, a3 = 0.f;
    float a4 = 0.f, a5 = 0.f, a6 = 0.f, a7 = 0.f;
    int n = s;
    for (; n + 8 <= e; n += 8) {
        a0 += xs[(long)(n + 0) * LD + d];
        a1 += xs[(long)(n + 1) * LD + d];
        a2 += xs[(long)(n + 2) * LD + d];
        a3 += xs[(long)(n + 3) * LD + d];
        a4 += xs[(long)(n + 4) * LD + d];
        a5 += xs[(long)(n + 5) * LD + d];
        a6 += xs[(long)(n + 6) * LD + d];
        a7 += xs[(long)(n + 7) * LD + d];
    }
    for (; n < e; ++n) a0 += xs[(long)n * LD + d];
    float acc = ((a0 + a1) + (a2 + a3)) + ((a4 + a5) + (a6 + a7));
    outpool[(long)g * LD + d] = acc / fmaxf((float)(e - s), 1.f);
}

// ---------------------------------------------------------------------------
static inline size_t rup(size_t x) { return (x + 255) & ~(size_t)255; }

extern "C" void kernel_launch(void* const* d_in, const int* in_sizes, int n_in,
                              void* d_out, int out_size, void* d_ws, size_t ws_size,
                              hipStream_t stream) {
    const float* x     = (const float*)d_in[0];
    const int*   ei    = (const int*)d_in[1];
    const int*   batch = (const int*)d_in[2];
    const float* W1    = (const float*)d_in[3];
    const float* b1    = (const float*)d_in[4];
    const float* W2    = (const float*)d_in[5];
    const float* b2    = (const float*)d_in[6];
    const float* gamma = (const float*)d_in[7];
    const float* beta  = (const float*)d_in[8];

    float* out      = (float*)d_out;
    float* out_pool = out;                                      // 256 x 320
    float* out_xs   = out + (size_t)NUM_GRAPHS * DIM * NLAYERS; // 100000 x 320

    char* w = (char*)d_ws;
    int*   csr      = (int*)w;    w += rup((size_t)N_NODES * CSR_CAP * 4);
    int*   cursor   = (int*)w;    w += rup((size_t)N_NODES * 4);
    int*   ovcnt    = (int*)w;    w += 256;
    int*   ovpairs  = (int*)w;    w += rup((size_t)OV_CAP * 8);
    float* agg      = (float*)w;  w += rup((size_t)N_NODES * DIM * 4);
    float* bufB     = (float*)w;  w += rup((size_t)N_NODES * DIM * 4);
    float* partials = (float*)w;  w += rup((size_t)STATS_BLOCKS * 128 * 4);
    float* ss       = (float*)w;  w += 512;
    int*   starts   = (int*)w;    w += rup((size_t)(NUM_GRAPHS + 1) * 4);

    hipMemsetAsync(cursor, 0, (size_t)N_NODES * 4, stream);
    hipMemsetAsync(ovcnt, 0, 4, stream);
    for (int sh = 0; sh < NSHARD; ++sh) {
        build_csr_shard_kernel<<<(N_EDGES + 255) / 256, 256, 0, stream>>>(
            ei, cursor, csr, ovcnt, ovpairs, sh * SHARD_W, (sh + 1) * SHARD_W);
    }
    pad_csr_kernel<<<NBLK, 256, 0, stream>>>(cursor, csr);
    graph_starts_kernel<<<1, 320, 0, stream>>>(batch, starts);

    const float* h = x;
    int hs = DIM;
    for (int l = 0; l < NLAYERS; ++l) {
        aggregate_kernel<<<((long)N_NODES * DIM + 255) / 256, 256, 0, stream>>>(
            csr, cursor, ovcnt, ovpairs, h, hs, agg);
        mlp_gemm_kernel<<<NBLK, 256, 0, stream>>>(
            agg, W1 + (size_t)l * DIM * DIM, b1 + (size_t)l * DIM, bufB);
        mlp_gemm_kernel<<<NBLK, 256, 0, stream>>>(
            bufB, W2 + (size_t)l * DIM * DIM, b2 + (size_t)l * DIM, agg);
        stats_partial_kernel<<<STATS_BLOCKS, 256, 0, stream>>>(agg, partials);
        stats_finalize_kernel<<<1, 256, 0, stream>>>(partials, gamma + (size_t)l * DIM,
                                                     beta + (size_t)l * DIM, ss);
        bn_apply_kernel<<<((long)N_NODES * (DIM / 4) + 255) / 256, 256, 0, stream>>>(
            agg, ss, out_xs + (size_t)l * DIM);
        h = out_xs + (size_t)l * DIM;
        hs = DIM * NLAYERS;
    }

    pool_kernel<<<NUM_GRAPHS, 320, 0, stream>>>(out_xs, starts, out_pool);
}